// Round 5
// baseline (282.077 us; speedup 1.0000x reference)
//
#include <hip/hip_runtime.h>
#include <math.h>

#define Bc     16
#define HIDc   2048
#define Hc     32
#define Dc     64
#define KVc    4096
#define QKVO   6144        // 3*H*D
#define SCALEc 0.125f      // D^-0.5
#define CHUNKS 4
#define CHUNK  1024        // KVc / CHUNKS

// ---------------- Kernel 1: qkv[b][o] = sum_h x[b][h] * w_qkv[o][h] ----------------
__global__ __launch_bounds__(256) void qkv_kernel(const float* __restrict__ x,
                                                  const float* __restrict__ w,
                                                  float* __restrict__ qkv) {
    __shared__ float4 xs[512];   // 8 KB
    int blk = blockIdx.x;        // 16 b * 96 ogroups = 1536
    int b   = blk & 15;
    int og  = blk >> 4;
    int t = threadIdx.x, lane = t & 63, wid = t >> 6;
    const float4* xr = reinterpret_cast<const float4*>(x + (size_t)b * HIDc);
    xs[t]       = xr[t];
    xs[t + 256] = xr[t + 256];
    __syncthreads();
    int o0 = og * 64 + wid * 16;
#pragma unroll 2
    for (int i = 0; i < 16; ++i) {
        int o = o0 + i;
        const float4* wr = reinterpret_cast<const float4*>(w + (size_t)o * HIDc);
        float acc = 0.f;
#pragma unroll
        for (int j = 0; j < 8; ++j) {
            float4 a = xs[lane + 64 * j];
            float4 c = wr[lane + 64 * j];
            acc += a.x * c.x + a.y * c.y + a.z * c.z + a.w * c.w;
        }
#pragma unroll
        for (int off = 32; off >= 1; off >>= 1) acc += __shfl_xor(acc, off);
        if (lane == 0) qkv[(size_t)b * QKVO + o] = acc;
    }
}

// ---------------- Kernel 2a: one-pass chunked attention (flash-decoding) ----------------
// grid = B*H*CHUNKS = 2048 blocks, 256 threads. (256,4): 128-VGPR cap, no spill.
// Per iteration each wave issues 16 coalesced float4 loads (8 K rows + 8 V rows =
// 16 KB) before any compute; softmax state rescaled ONCE per 8-row group.
__global__ __launch_bounds__(256, 4) void attn_chunk_kernel(const float* __restrict__ qkv,
                                                            const float* __restrict__ bias,
                                                            const float* __restrict__ past_kv,
                                                            float* __restrict__ part_o,
                                                            float* __restrict__ part_ms) {
    __shared__ float bs[CHUNK];       // bias slice, 4 KB
    __shared__ float accs[16][65];    // subgroup partial O (padded)
    __shared__ float pm[16], ps[16];

    int blk = blockIdx.x;
    int c   = blk & (CHUNKS - 1);
    int bh  = blk >> 2;               // b*32 + h
    int h   = bh & 31;
    int b   = bh >> 5;
    int t    = threadIdx.x;
    int lane = t & 63;
    int wid  = t >> 6;
    int sg   = lane >> 4;
    int cg   = lane & 15;
    int row0 = c * CHUNK;

    // stage bias chunk into LDS (coalesced float4)
    reinterpret_cast<float4*>(bs)[t] =
        reinterpret_cast<const float4*>(bias + (size_t)bh * KVc + row0)[t];

    const float* qp = qkv + (size_t)b * QKVO + h * Dc;
    float4 q4 = reinterpret_cast<const float4*>(qp)[cg];

    const size_t kvstride = (size_t)KVc * Dc;
    const float* pastK = past_kv + (size_t)bh * kvstride + (size_t)row0 * Dc;
    const float* pastV = past_kv + (size_t)(Bc * Hc) * kvstride + (size_t)bh * kvstride
                         + (size_t)row0 * Dc;

    __syncthreads();

    int rbase = wid * 4 + sg;         // 16 subgroups cover 16 consecutive rows
    float m = -1e30f, s = 0.f;
    float4 acc = {0.f, 0.f, 0.f, 0.f};

    // 8 groups of 128 rows; last group of last chunk peeled (new-token row)
    int nclean = (c == CHUNKS - 1) ? 7 : 8;
    for (int ot = 0; ot < nclean; ++ot) {
        int it = ot * 8;
        float4 k4[8], v4[8];
#pragma unroll
        for (int u = 0; u < 8; ++u) {
            int rl = (it + u) * 16 + rbase;
            k4[u] = reinterpret_cast<const float4*>(pastK + (size_t)rl * Dc)[cg];
        }
#pragma unroll
        for (int u = 0; u < 8; ++u) {
            int rl = (it + u) * 16 + rbase;
            v4[u] = reinterpret_cast<const float4*>(pastV + (size_t)rl * Dc)[cg];
        }
        float p[8];
#pragma unroll
        for (int u = 0; u < 8; ++u) {
            int rl = (it + u) * 16 + rbase;
            float pp = q4.x * k4[u].x + q4.y * k4[u].y + q4.z * k4[u].z + q4.w * k4[u].w;
            pp += __shfl_xor(pp, 1);
            pp += __shfl_xor(pp, 2);
            pp += __shfl_xor(pp, 4);
            pp += __shfl_xor(pp, 8);
            p[u] = fmaf(pp, SCALEc, bs[rl]);
        }
        float gm = p[0];
#pragma unroll
        for (int u = 1; u < 8; ++u) gm = fmaxf(gm, p[u]);
        float mn  = fmaxf(m, gm);
        float scl = __expf(m - mn);
        m = mn;
        float es = 0.f;
        float4 va = {0.f, 0.f, 0.f, 0.f};
#pragma unroll
        for (int u = 0; u < 8; ++u) {
            float e = __expf(p[u] - mn);
            es += e;
            va.x = fmaf(e, v4[u].x, va.x);
            va.y = fmaf(e, v4[u].y, va.y);
            va.z = fmaf(e, v4[u].z, va.z);
            va.w = fmaf(e, v4[u].w, va.w);
        }
        s = fmaf(s, scl, es);
        acc.x = fmaf(acc.x, scl, va.x);
        acc.y = fmaf(acc.y, scl, va.y);
        acc.z = fmaf(acc.z, scl, va.z);
        acc.w = fmaf(acc.w, scl, va.w);
    }
    if (c == CHUNKS - 1) {
        // rows 896..1023 of the chunk; local row CHUNK-1 is the new K/V token
        const float* knew = qkv + (size_t)b * QKVO + HIDc + h * Dc;
        const float* vnew = qkv + (size_t)b * QKVO + 2 * HIDc + h * Dc;
        int it = 56;
        float4 k4[8], v4[8];
#pragma unroll
        for (int u = 0; u < 8; ++u) {
            int rl = (it + u) * 16 + rbase;
            const float* kr = (rl == CHUNK - 1) ? knew : (pastK + (size_t)rl * Dc);
            k4[u] = reinterpret_cast<const float4*>(kr)[cg];
        }
#pragma unroll
        for (int u = 0; u < 8; ++u) {
            int rl = (it + u) * 16 + rbase;
            const float* vr = (rl == CHUNK - 1) ? vnew : (pastV + (size_t)rl * Dc);
            v4[u] = reinterpret_cast<const float4*>(vr)[cg];
        }
        float p[8];
#pragma unroll
        for (int u = 0; u < 8; ++u) {
            int rl = (it + u) * 16 + rbase;
            float pp = q4.x * k4[u].x + q4.y * k4[u].y + q4.z * k4[u].z + q4.w * k4[u].w;
            pp += __shfl_xor(pp, 1);
            pp += __shfl_xor(pp, 2);
            pp += __shfl_xor(pp, 4);
            pp += __shfl_xor(pp, 8);
            p[u] = fmaf(pp, SCALEc, bs[rl]);
        }
        float gm = p[0];
#pragma unroll
        for (int u = 1; u < 8; ++u) gm = fmaxf(gm, p[u]);
        float mn  = fmaxf(m, gm);
        float scl = __expf(m - mn);
        m = mn;
        float es = 0.f;
        float4 va = {0.f, 0.f, 0.f, 0.f};
#pragma unroll
        for (int u = 0; u < 8; ++u) {
            float e = __expf(p[u] - mn);
            es += e;
            va.x = fmaf(e, v4[u].x, va.x);
            va.y = fmaf(e, v4[u].y, va.y);
            va.z = fmaf(e, v4[u].z, va.z);
            va.w = fmaf(e, v4[u].w, va.w);
        }
        s = fmaf(s, scl, es);
        acc.x = fmaf(acc.x, scl, va.x);
        acc.y = fmaf(acc.y, scl, va.y);
        acc.z = fmaf(acc.z, scl, va.z);
        acc.w = fmaf(acc.w, scl, va.w);
    }

    // merge 16 subgroup partials within the block
    int sgid = wid * 4 + sg;
    if (cg == 0) { pm[sgid] = m; ps[sgid] = s; }
    accs[sgid][cg * 4 + 0] = acc.x;
    accs[sgid][cg * 4 + 1] = acc.y;
    accs[sgid][cg * 4 + 2] = acc.z;
    accs[sgid][cg * 4 + 3] = acc.w;
    __syncthreads();
    if (t < 64) {
        float M = pm[0];
#pragma unroll
        for (int i = 1; i < 16; ++i) M = fmaxf(M, pm[i]);
        float S = 0.f, o = 0.f;
#pragma unroll
        for (int i = 0; i < 16; ++i) {
            float w = __expf(pm[i] - M);
            S += w * ps[i];
            o += w * accs[i][t];
        }
        part_o[((size_t)bh * CHUNKS + c) * Dc + t] = o;
        if (t == 0) {
            part_ms[((size_t)bh * CHUNKS + c) * 2 + 0] = M;
            part_ms[((size_t)bh * CHUNKS + c) * 2 + 1] = S;
        }
    }
}

// ---------------- Kernel 2b: combine chunk partials ----------------
__global__ __launch_bounds__(64) void attn_combine_kernel(const float* __restrict__ part_o,
                                                          const float* __restrict__ part_ms,
                                                          float* __restrict__ attn_out) {
    int bh = blockIdx.x;
    int d  = threadIdx.x;
    float mc[CHUNKS], sc_[CHUNKS];
#pragma unroll
    for (int c = 0; c < CHUNKS; ++c) {
        mc[c]  = part_ms[((size_t)bh * CHUNKS + c) * 2 + 0];
        sc_[c] = part_ms[((size_t)bh * CHUNKS + c) * 2 + 1];
    }
    float M = mc[0];
#pragma unroll
    for (int c = 1; c < CHUNKS; ++c) M = fmaxf(M, mc[c]);
    float S = 0.f, o = 0.f;
#pragma unroll
    for (int c = 0; c < CHUNKS; ++c) {
        float w = __expf(mc[c] - M);
        S += w * sc_[c];
        o += w * part_o[((size_t)bh * CHUNKS + c) * Dc + d];
    }
    attn_out[(size_t)bh * Dc + d] = o / S;
}

// ---------------- Kernel 3: out[b][f] = sum_c attn[b][c] * w_o[f][c] ----------------
__global__ __launch_bounds__(256) void outproj_kernel(const float* __restrict__ attn,
                                                      const float* __restrict__ w_o,
                                                      float* __restrict__ out) {
    __shared__ float4 as[512];   // 8 KB
    int blk = blockIdx.x;        // 16 b * 32 fgroups = 512
    int b   = blk & 15;
    int fg  = blk >> 4;
    int t = threadIdx.x, lane = t & 63, wid = t >> 6;
    const float4* ar = reinterpret_cast<const float4*>(attn + (size_t)b * HIDc);
    as[t]       = ar[t];
    as[t + 256] = ar[t + 256];
    __syncthreads();
    int f0 = fg * 64 + wid * 16;
#pragma unroll 2
    for (int i = 0; i < 16; ++i) {
        int f = f0 + i;
        const float4* wr = reinterpret_cast<const float4*>(w_o + (size_t)f * HIDc);
        float acc = 0.f;
#pragma unroll
        for (int j = 0; j < 8; ++j) {
            float4 a = as[lane + 64 * j];
            float4 c = wr[lane + 64 * j];
            acc += a.x * c.x + a.y * c.y + a.z * c.z + a.w * c.w;
        }
#pragma unroll
        for (int off = 32; off >= 1; off >>= 1) acc += __shfl_xor(acc, off);
        if (lane == 0) out[(size_t)b * HIDc + f] = acc;
    }
}

extern "C" void kernel_launch(void* const* d_in, const int* in_sizes, int n_in,
                              void* d_out, int out_size, void* d_ws, size_t ws_size,
                              hipStream_t stream) {
    const float* x       = (const float*)d_in[0];
    const float* bias    = (const float*)d_in[1];
    const float* past_kv = (const float*)d_in[2];
    const float* w_qkv   = (const float*)d_in[3];
    const float* w_o     = (const float*)d_in[4];
    float* out = (float*)d_out;

    float* qkv     = (float*)d_ws;                           // 16*6144
    float* attn    = qkv + (size_t)Bc * QKVO;                // 16*2048
    float* part_o  = attn + (size_t)Bc * HIDc;               // 16*32*4*64
    float* part_ms = part_o + (size_t)Bc * Hc * CHUNKS * Dc; // 16*32*4*2

    qkv_kernel<<<dim3(Bc * (QKVO / 64)), dim3(256), 0, stream>>>(x, w_qkv, qkv);
    attn_chunk_kernel<<<dim3(Bc * Hc * CHUNKS), dim3(256), 0, stream>>>(qkv, bias, past_kv, part_o, part_ms);
    attn_combine_kernel<<<dim3(Bc * Hc), dim3(64), 0, stream>>>(part_o, part_ms, attn);
    outproj_kernel<<<dim3(Bc * (HIDc / 64)), dim3(256), 0, stream>>>(attn, w_o, out);
}